// Round 6
// baseline (354.555 us; speedup 1.0000x reference)
//
#include <hip/hip_runtime.h>
#include <hip/hip_bf16.h>

#define N_NODES 100000
#define N_EDGES 262144
#define IN_DIM 768
#define HIDDEN 256
#define BM 48
#define NK 24                  // 768 / 32
#define M_BLOCKS 2084          // ceil(100000/48)
#define M_PAD (M_BLOCKS * BM)  // 100032

typedef __attribute__((ext_vector_type(8))) short short8;
typedef __attribute__((ext_vector_type(4))) float f32x4;

__device__ __forceinline__ unsigned short f32_to_bf16(float f) {
    unsigned int u = __builtin_bit_cast(unsigned int, f);
    u = (u + 0x7FFFu + ((u >> 16) & 1u)) >> 16;
    return (unsigned short)u;
}
__device__ __forceinline__ float bf16_to_f32(unsigned short h) {
    unsigned int u = ((unsigned int)h) << 16;
    return __builtin_bit_cast(float, u);
}

// Wt[g][n][k] = bf16(W1[g*768 + k][n]) ; k-contiguous for 16B fragment loads
__global__ __launch_bounds__(256) void convert_w1(const float* __restrict__ W1,
                                                  unsigned short* __restrict__ Wt) {
    int t = blockIdx.x * blockDim.x + threadIdx.x;
    if (t >= 2 * HIDDEN * IN_DIM) return;
    int k = t % IN_DIM;
    int n = (t / IN_DIM) % HIDDEN;
    int g = t / (IN_DIM * HIDDEN);
    Wt[t] = f32_to_bf16(W1[(size_t)(g * IN_DIM + k) * HIDDEN + n]);
}

// P = bf16(X) @ bf16(W1half). Block = 48 rows x 256 cols x full K.
// Phase 1: load the block's CONTIGUOUS 147KB X-panel (1KB/wave-inst, m13
// pattern), convert once, store to swizzled LDS. Phase 2 (barrier-free):
// 24 k-steps of LDS A-frags + L2-resident global B-frags + MFMA.
__global__ __launch_bounds__(512, 4) void node_gemm(const float* __restrict__ X0,
                                                    const float* __restrict__ X1,
                                                    const unsigned short* __restrict__ WtAll,
                                                    unsigned short* __restrict__ Pout,
                                                    unsigned short* __restrict__ Qout) {
    const int g = blockIdx.y;
    const float* __restrict__ X = g ? X1 : X0;
    const unsigned short* __restrict__ Wt = WtAll + (size_t)g * IN_DIM * HIDDEN;
    unsigned short* __restrict__ Out = g ? Qout : Pout;

    // A panel: 48 rows x 768 k bf16, row stride 1536B.
    // Within each row, k is stored in 128B windows of 2 k-steps (8 granules
    // of 16B); granule index gi = ((ks&1)*4 + c) ^ (row&7)  -> balanced banks.
    __shared__ __attribute__((aligned(16))) char A[BM * IN_DIM * 2]; // 73728 B

    const int m0   = blockIdx.x * BM;
    const int tid  = threadIdx.x;
    const int lane = tid & 63;
    const int wn   = tid >> 6;   // wave id 0..7 -> 32-col slab
    const int lr   = lane & 15;
    const int c    = lane >> 4;  // 0..3

    // ---- Phase 1: contiguous panel stage (18 passes x 8KB/block)
    {
        const size_t fbase = (size_t)m0 * IN_DIM;
        const long fmax = (long)N_NODES * IN_DIM - 4;
#pragma unroll
        for (int p = 0; p < 18; ++p) {
            long fi = (long)fbase + p * 2048 + tid * 4;
            if (fi > fmax) fi = fmax;            // tail block clamp (16B aligned)
            float4 v = *(const float4*)(X + fi);
            int li  = p * 2048 + tid * 4;        // panel-local float index
            int row = li / IN_DIM;
            int col = li - row * IN_DIM;
            int ks  = col >> 5;
            int cw  = (col >> 3) & 3;
            int j   = col & 7;
            int gi  = (((ks & 1) << 2) | cw) ^ (row & 7);
            int boff = row * 1536 + (ks >> 1) * 128 + (gi << 4) + j * 2;
            ushort4 w;
            w.x = f32_to_bf16(v.x); w.y = f32_to_bf16(v.y);
            w.z = f32_to_bf16(v.z); w.w = f32_to_bf16(v.w);
            *(ushort4*)(A + boff) = w;
        }
    }
    __syncthreads();

    // ---- Phase 2: barrier-free compute. Wave tile = 48m x 32n.
    f32x4 acc[3][2] = {};

    // B fragment base pointers (global, L2-resident), one per ni
    const unsigned short* bptr0 = Wt + (size_t)(wn * 32 + lr) * IN_DIM + c * 8;
    const unsigned short* bptr1 = bptr0 + (size_t)16 * IN_DIM;
    // A fragment lane bases, per mi and ks-parity
    int abase[3][2];
#pragma unroll
    for (int mi = 0; mi < 3; ++mi) {
        int r = mi * 16 + lr;
#pragma unroll
        for (int par = 0; par < 2; ++par) {
            int gi = ((par << 2) | c) ^ (r & 7);
            abase[mi][par] = r * 1536 + (gi << 4);
        }
    }

#pragma unroll 4
    for (int ks = 0; ks < NK; ++ks) {
        short8 bfr0 = *(const short8*)(bptr0 + ks * 32);
        short8 bfr1 = *(const short8*)(bptr1 + ks * 32);
        short8 afr[3];
#pragma unroll
        for (int mi = 0; mi < 3; ++mi)
            afr[mi] = *(const short8*)(A + abase[mi][ks & 1] + (ks >> 1) * 128);
#pragma unroll
        for (int mi = 0; mi < 3; ++mi) {
            // swapped operands: D[n][m] -> lane holds 4 consecutive n-cols
            acc[mi][0] = __builtin_amdgcn_mfma_f32_16x16x32_bf16(bfr0, afr[mi], acc[mi][0], 0, 0, 0);
            acc[mi][1] = __builtin_amdgcn_mfma_f32_16x16x32_bf16(bfr1, afr[mi], acc[mi][1], 0, 0, 0);
        }
    }

    // store: m = m0 + mi*16 + lr, n = wn*32 + ni*16 + c*4 + reg
#pragma unroll
    for (int mi = 0; mi < 3; ++mi) {
        size_t mg = (size_t)(m0 + mi * 16 + lr);   // < M_PAD, pad rows harmless
#pragma unroll
        for (int ni = 0; ni < 2; ++ni) {
            f32x4 a = acc[mi][ni];
            ushort4 w;
            w.x = f32_to_bf16(a[0]); w.y = f32_to_bf16(a[1]);
            w.z = f32_to_bf16(a[2]); w.w = f32_to_bf16(a[3]);
            *(ushort4*)(Out + mg * HIDDEN + wn * 32 + ni * 16 + c * 4) = w;
        }
    }
}

// out[e] = relu(P[s]+Q[d]+b1) . W2 + b2 ; one wave per edge, lane j owns dims 4j..4j+3
__global__ __launch_bounds__(256) void edge_mlp(const unsigned short* __restrict__ P,
                                                const unsigned short* __restrict__ Q,
                                                const int* __restrict__ s_idx,
                                                const int* __restrict__ d_idx,
                                                const float* __restrict__ b1,
                                                const float* __restrict__ W2,
                                                const float* __restrict__ b2,
                                                float* __restrict__ out) {
    const int lane = threadIdx.x & 63;
    const int gw = (blockIdx.x * blockDim.x + threadIdx.x) >> 6;
    const int nw = (gridDim.x * blockDim.x) >> 6;
    const float4 b1v = *(const float4*)(b1 + lane * 4);
    const float4 w2v = *(const float4*)(W2 + lane * 4);
    const float b2s = *b2;
    for (int e = gw; e < N_EDGES; e += nw) {
        int s = s_idx[e];
        int d = d_idx[e];
        ushort4 pv = *(const ushort4*)(P + (size_t)s * HIDDEN + lane * 4);
        ushort4 qv = *(const ushort4*)(Q + (size_t)d * HIDDEN + lane * 4);
        float h, sum;
        h = bf16_to_f32(pv.x) + bf16_to_f32(qv.x) + b1v.x; h = fmaxf(h, 0.f); sum  = h * w2v.x;
        h = bf16_to_f32(pv.y) + bf16_to_f32(qv.y) + b1v.y; h = fmaxf(h, 0.f); sum += h * w2v.y;
        h = bf16_to_f32(pv.z) + bf16_to_f32(qv.z) + b1v.z; h = fmaxf(h, 0.f); sum += h * w2v.z;
        h = bf16_to_f32(pv.w) + bf16_to_f32(qv.w) + b1v.w; h = fmaxf(h, 0.f); sum += h * w2v.w;
#pragma unroll
        for (int off = 32; off; off >>= 1) sum += __shfl_xor(sum, off, 64);
        if (lane == 0) out[e] = sum + b2s;
    }
}

extern "C" void kernel_launch(void* const* d_in, const int* in_sizes, int n_in,
                              void* d_out, int out_size, void* d_ws, size_t ws_size,
                              hipStream_t stream) {
    const float* x_src = (const float*)d_in[0];
    const float* x_dst = (const float*)d_in[1];
    const int*   s_idx = (const int*)d_in[2];
    const int*   d_idx = (const int*)d_in[3];
    const float* W1    = (const float*)d_in[4];
    const float* b1    = (const float*)d_in[5];
    const float* W2    = (const float*)d_in[6];
    const float* b2    = (const float*)d_in[7];
    float* out = (float*)d_out;

    char* ws = (char*)d_ws;
    // layout: Wt (786432 B) | P (M_PAD*256*2 B) | Q (M_PAD*256*2 B) => ~103.2 MB
    unsigned short* Wt = (unsigned short*)ws;
    unsigned short* P  = (unsigned short*)(ws + 786432);
    unsigned short* Q  = (unsigned short*)(ws + 786432 + (size_t)M_PAD * HIDDEN * 2);

    convert_w1<<<(2 * IN_DIM * HIDDEN + 255) / 256, 256, 0, stream>>>(W1, Wt);

    dim3 gg(M_BLOCKS, 2);
    node_gemm<<<gg, 512, 0, stream>>>(x_src, x_dst, Wt, P, Q);

    edge_mlp<<<2048, 256, 0, stream>>>(P, Q, s_idx, d_idx, b1, W2, b2, out);
}

// Round 8
// 272.688 us; speedup vs baseline: 1.3002x; 1.3002x over previous
//
#include <hip/hip_runtime.h>
#include <hip/hip_bf16.h>

#define N_NODES 100000
#define N_EDGES 262144
#define IN_DIM 768
#define HIDDEN 256
#define BM 256
#define BN 256
#define BK 64
#define NK (IN_DIM / BK)       // 12
#define M_BLOCKS 391           // ceil(100000/256)
#define M_PAD (M_BLOCKS * BM)  // 100096
#define WT_TILE_BYTES (BN * BK * 2) // 32768

typedef __attribute__((ext_vector_type(8))) short short8;
typedef __attribute__((ext_vector_type(4))) float f32x4;

#define WAITV(n) asm volatile("s_waitcnt vmcnt(" #n ")" ::: "memory")
#define LGKM0()  asm volatile("s_waitcnt lgkmcnt(0)" ::: "memory")
#define BAR()    __builtin_amdgcn_s_barrier()

__device__ __forceinline__ unsigned short f32_to_bf16(float f) {
    unsigned int u = __builtin_bit_cast(unsigned int, f);
    u = (u + 0x7FFFu + ((u >> 16) & 1u)) >> 16;
    return (unsigned short)u;
}
__device__ __forceinline__ float bf16_to_f32(unsigned short h) {
    unsigned int u = ((unsigned int)h) << 16;
    return __builtin_bit_cast(float, u);
}
__device__ __forceinline__ void gload_lds16(const void* gsrc, void* lds) {
    __builtin_amdgcn_global_load_lds(
        (const __attribute__((address_space(1))) unsigned int*)gsrc,
        (__attribute__((address_space(3))) unsigned int*)lds,
        16, 0, 0);
}

// WtT layout [g][kt][n][p][j]: granule p of row n holds logical granule
// p ^ (n&7), i.e. k = kt*64 + (p^(n&7))*8 + j. A LINEAR global_load_lds
// write then yields the LDS tile read with granule ^= (n&7).
__global__ __launch_bounds__(256) void convert_w1(const float* __restrict__ W1,
                                                  unsigned short* __restrict__ WtT) {
    int t = blockIdx.x * blockDim.x + threadIdx.x;
    if (t >= 2 * NK * BN * BK) return;
    int g  = t / (NK * BN * BK);
    int r  = t - g * (NK * BN * BK);
    int kt = r >> 14;            // BN*BK = 16384
    int n  = (r >> 6) & 255;
    int p  = (r >> 3) & 7;
    int j  = r & 7;
    int k  = kt * BK + ((p ^ (n & 7)) << 3) + j;
    WtT[t] = f32_to_bf16(W1[(size_t)(g * IN_DIM + k) * HIDDEN + n]);
}

// P = bf16(X) @ bf16(W1half). 256x256 tile, BK=64, 8 waves (wave = 128m x 64n).
// m201-style 4-phase K-tile schedule: per phase {ds_read frags | stage issue |
// barrier | lgkm0 | setprio1 | 16 MFMA | setprio0 | barrier}. Counted vmcnt
// only (4 then 8), never 0 in the loop.
__global__ __launch_bounds__(512, 2) void node_gemm(const float* __restrict__ X0,
                                                    const float* __restrict__ X1,
                                                    const unsigned short* __restrict__ WtT,
                                                    unsigned short* __restrict__ Pout,
                                                    unsigned short* __restrict__ Qout) {
    const int g = blockIdx.y;
    const float* __restrict__ X = g ? X1 : X0;
    unsigned short* __restrict__ Out = g ? Qout : Pout;
    const char* wt_base = (const char*)WtT + (size_t)g * NK * WT_TILE_BYTES;

    // 256 rows x 8 granules x 16B = 128B/row, granule-XOR swizzled
    __shared__ __attribute__((aligned(16))) char As[2][BM * BK * 2]; // 2x32KB
    __shared__ __attribute__((aligned(16))) char Bs[2][BN * BK * 2]; // 2x32KB

    const int m0   = blockIdx.x * BM;
    const int tid  = threadIdx.x;
    const int lane = tid & 63;
    const int wid  = tid >> 6;
    const int wm   = wid >> 2;  // 0..1 -> 128-row slab
    const int wn   = wid & 3;   // 0..3 -> 64-col slab
    const int lr   = lane & 15;
    const int c    = lane >> 4; // 0..3

    // A staging coords: lane owns rows wid*32 + q*8 + (lane>>3), f32 granule g8
    const int srow = wid * 32 + (lane >> 3);
    const int g8   = lane & 7;

    f32x4 acc[8][4] = {};
    float4 st[4][2];

    auto loadA_half = [&](int kt, int h) {
        const int k0 = kt * BK;
#pragma unroll
        for (int q = 2 * h; q < 2 * h + 2; ++q) {
            int r  = srow + q * 8;
            int rg = m0 + r;
            if (rg >= N_NODES) rg = N_NODES - 1;
            const float* p = X + (size_t)rg * IN_DIM + k0 + g8 * 8;
            st[q][0] = *(const float4*)(p);
            st[q][1] = *(const float4*)(p + 4);
        }
    };
    auto writeA = [&](char* wrA) {
#pragma unroll
        for (int q = 0; q < 4; ++q) {
            int r  = srow + q * 8;
            int gs = g8 ^ (r & 7);
            short8 w;
            w[0] = (short)f32_to_bf16(st[q][0].x); w[1] = (short)f32_to_bf16(st[q][0].y);
            w[2] = (short)f32_to_bf16(st[q][0].z); w[3] = (short)f32_to_bf16(st[q][0].w);
            w[4] = (short)f32_to_bf16(st[q][1].x); w[5] = (short)f32_to_bf16(st[q][1].y);
            w[6] = (short)f32_to_bf16(st[q][1].z); w[7] = (short)f32_to_bf16(st[q][1].w);
            *(short8*)(wrA + r * 128 + (gs << 4)) = w;
        }
    };
    auto issueB = [&](int kt, char* wrB) {
        // 32KB tile / 512 threads = 4 x 16B per lane; wave covers 4KB
        const char* src = wt_base + (size_t)kt * WT_TILE_BYTES + wid * 4096 + lane * 16;
        char* dst = wrB + wid * 4096;   // wave-uniform; HW adds lane*16
#pragma unroll
        for (int j = 0; j < 4; ++j)
            gload_lds16(src + j * 1024, dst + j * 1024);
    };
    auto readA = [&](const char* rdA, int kk, short8 (&afr)[8]) {
#pragma unroll
        for (int mi = 0; mi < 8; ++mi) {
            int r  = wm * 128 + mi * 16 + lr;
            int gs = (kk * 4 + c) ^ (r & 7);
            afr[mi] = *(const short8*)(rdA + r * 128 + (gs << 4));
        }
    };
    auto readB = [&](const char* rdB, int ni, int kk) -> short8 {
        int n  = wn * 64 + ni * 16 + lr;
        int gs = (kk * 4 + c) ^ (n & 7);
        return *(const short8*)(rdB + n * 128 + (gs << 4));
    };
    auto mfma16 = [&](const short8 (&afr)[8], const short8 b0, const short8 b1, int nb) {
        __builtin_amdgcn_s_setprio(1);
#pragma unroll
        for (int mi = 0; mi < 8; ++mi) {
            acc[mi][nb]     = __builtin_amdgcn_mfma_f32_16x16x32_bf16(b0, afr[mi], acc[mi][nb], 0, 0, 0);
            acc[mi][nb + 1] = __builtin_amdgcn_mfma_f32_16x16x32_bf16(b1, afr[mi], acc[mi][nb + 1], 0, 0, 0);
        }
        __builtin_amdgcn_s_setprio(0);
    };

    auto tile = [&](int t, const char* rdA, const char* rdB, char* wrA, char* wrB) {
        const int kB = (t + 1 < NK) ? t + 1 : NK - 1;
        const int kA = (t + 2 < NK) ? t + 2 : NK - 1;
        short8 afr[8], b0, b1;
        // ---- phase 0: A(kk0) + B(0,1|kk0) reads; issue B(t+1)  [+4 vm]
        readA(rdA, 0, afr);
        b0 = readB(rdB, 0, 0); b1 = readB(rdB, 1, 0);
        issueB(kB, wrB);
        BAR(); LGKM0();
        mfma16(afr, b0, b1, 0);
        BAR();
        // ---- phase 1: B(2,3|kk0); vmcnt(4) -> A(t+1) regs landed; ds_write A(t+1)
        b0 = readB(rdB, 2, 0); b1 = readB(rdB, 3, 0);
        WAITV(4);
        writeA(wrA);
        BAR(); LGKM0();
        mfma16(afr, b0, b1, 2);
        BAR();
        // ---- phase 2: A(kk1) + B(0,1|kk1); issue first half of A(t+2) [+4 vm]
        readA(rdA, 1, afr);
        b0 = readB(rdB, 0, 1); b1 = readB(rdB, 1, 1);
        loadA_half(kA, 0);
        BAR(); LGKM0();
        mfma16(afr, b0, b1, 0);
        BAR();
        // ---- phase 3: B(2,3|kk1); 2nd half A(t+2) [+4 vm]; vmcnt(8) -> B(t+1) landed
        b0 = readB(rdB, 2, 1); b1 = readB(rdB, 3, 1);
        loadA_half(kA, 1);
        WAITV(8);
        BAR(); LGKM0();
        mfma16(afr, b0, b1, 2);
        BAR();
    };

    // ---- prologue: A(0),B(0) staged; A(1) in regs/in flight
    loadA_half(0, 0); loadA_half(0, 1);
    issueB(0, Bs[0]);
    WAITV(0);
    writeA(As[0]);
    loadA_half(1, 0); loadA_half(1, 1);
    LGKM0();
    BAR();

    for (int t2 = 0; t2 < NK; t2 += 2) {
        tile(t2,     As[0], Bs[0], As[1], Bs[1]);
        tile(t2 + 1, As[1], Bs[1], As[0], Bs[0]);
    }

    // store: m = m0 + wm*128 + mi*16 + lr, n = wn*64 + ni*16 + c*4 + reg
    const int mrow = wm * 128 + lr;
    const int nb0  = wn * 64 + (c << 2);
#pragma unroll
    for (int mi = 0; mi < 8; ++mi) {
        size_t mg = (size_t)(m0 + mrow + mi * 16);
#pragma unroll
        for (int ni = 0; ni < 4; ++ni) {
            f32x4 a = acc[mi][ni];
            ushort4 w;
            w.x = f32_to_bf16(a[0]); w.y = f32_to_bf16(a[1]);
            w.z = f32_to_bf16(a[2]); w.w = f32_to_bf16(a[3]);
            *(ushort4*)(Out + mg * HIDDEN + nb0 + ni * 16) = w;
        }
    }
    WAITV(0);   // drain tail gload_lds before LDS is reallocated
}

// out[e] = relu(P[s]+Q[d]+b1) . W2 + b2 ; one wave per edge, lane j owns dims 4j..4j+3
__global__ __launch_bounds__(256) void edge_mlp(const unsigned short* __restrict__ P,
                                                const unsigned short* __restrict__ Q,
                                                const int* __restrict__ s_idx,
                                                const int* __restrict__ d_idx,
                                                const float* __restrict__ b1,
                                                const float* __restrict__ W2,
                                                const float* __restrict__ b2,
                                                float* __restrict__ out) {
    const int lane = threadIdx.x & 63;
    const int gw = (blockIdx.x * blockDim.x + threadIdx.x) >> 6;
    const int nw = (gridDim.x * blockDim.x) >> 6;
    const float4 b1v = *(const float4*)(b1 + lane * 4);
    const float4 w2v = *(const float4*)(W2 + lane * 4);
    const float b2s = *b2;
    for (int e = gw; e < N_EDGES; e += nw) {
        int s = s_idx[e];
        int d = d_idx[e];
        ushort4 pv = *(const ushort4*)(P + (size_t)s * HIDDEN + lane * 4);
        ushort4 qv = *(const ushort4*)(Q + (size_t)d * HIDDEN + lane * 4);
        float h, sum;
        h = bf16_to_f32(pv.x) + bf16_to_f32(qv.x) + b1v.x; h = fmaxf(h, 0.f); sum  = h * w2v.x;
        h = bf16_to_f32(pv.y) + bf16_to_f32(qv.y) + b1v.y; h = fmaxf(h, 0.f); sum += h * w2v.y;
        h = bf16_to_f32(pv.z) + bf16_to_f32(qv.z) + b1v.z; h = fmaxf(h, 0.f); sum += h * w2v.z;
        h = bf16_to_f32(pv.w) + bf16_to_f32(qv.w) + b1v.w; h = fmaxf(h, 0.f); sum += h * w2v.w;
#pragma unroll
        for (int off = 32; off; off >>= 1) sum += __shfl_xor(sum, off, 64);
        if (lane == 0) out[e] = sum + b2s;
    }
}

extern "C" void kernel_launch(void* const* d_in, const int* in_sizes, int n_in,
                              void* d_out, int out_size, void* d_ws, size_t ws_size,
                              hipStream_t stream) {
    const float* x_src = (const float*)d_in[0];
    const float* x_dst = (const float*)d_in[1];
    const int*   s_idx = (const int*)d_in[2];
    const int*   d_idx = (const int*)d_in[3];
    const float* W1    = (const float*)d_in[4];
    const float* b1    = (const float*)d_in[5];
    const float* W2    = (const float*)d_in[6];
    const float* b2    = (const float*)d_in[7];
    float* out = (float*)d_out;

    char* ws = (char*)d_ws;
    // layout: WtT (786432 B) | P (M_PAD*256*2 B) | Q (M_PAD*256*2 B) => ~103.3 MB
    unsigned short* WtT = (unsigned short*)ws;
    unsigned short* P   = (unsigned short*)(ws + 786432);
    unsigned short* Q   = (unsigned short*)(ws + 786432 + (size_t)M_PAD * HIDDEN * 2);

    convert_w1<<<(2 * NK * BN * BK + 255) / 256, 256, 0, stream>>>(W1, WtT);

    dim3 gg(M_BLOCKS, 2);
    node_gemm<<<gg, 512, 0, stream>>>(x_src, x_dst, WtT, P, Q);

    edge_mlp<<<2048, 256, 0, stream>>>(P, Q, s_idx, d_idx, b1, W2, b2, out);
}

// Round 9
// 254.008 us; speedup vs baseline: 1.3958x; 1.0735x over previous
//
#include <hip/hip_runtime.h>
#include <hip/hip_bf16.h>

#define N_NODES 100000
#define N_EDGES 262144
#define IN_DIM 768
#define HIDDEN 256
#define BM 128                 // rows per block = 4 waves x 32
#define BK 32
#define NK 24                  // 768/32
#define M_BLOCKS 782           // ceil(100000/128)
#define M_PAD (M_BLOCKS * BM)  // 100096
#define WTB_TILE 16384         // bytes per (g,ks) B slab: 256 n x 32 k x 2B

typedef __attribute__((ext_vector_type(8))) short short8;
typedef __attribute__((ext_vector_type(4))) float f32x4;

#define WAITV(n) asm volatile("s_waitcnt vmcnt(" #n ")" ::: "memory")
#define BAR()    __builtin_amdgcn_s_barrier()

__device__ __forceinline__ unsigned short f32_to_bf16(float f) {
    unsigned int u = __builtin_bit_cast(unsigned int, f);
    u = (u + 0x7FFFu + ((u >> 16) & 1u)) >> 16;
    return (unsigned short)u;
}
__device__ __forceinline__ float bf16_to_f32(unsigned short h) {
    unsigned int u = ((unsigned int)h) << 16;
    return __builtin_bit_cast(float, u);
}
__device__ __forceinline__ void gload_lds16(const void* gsrc, void* lds) {
    __builtin_amdgcn_global_load_lds(
        (const __attribute__((address_space(1))) unsigned int*)gsrc,
        (__attribute__((address_space(3))) unsigned int*)lds,
        16, 0, 0);
}
__device__ __forceinline__ short8 cvt8(float4 lo, float4 hi) {
    short8 w;
    w[0] = (short)f32_to_bf16(lo.x); w[1] = (short)f32_to_bf16(lo.y);
    w[2] = (short)f32_to_bf16(lo.z); w[3] = (short)f32_to_bf16(lo.w);
    w[4] = (short)f32_to_bf16(hi.x); w[5] = (short)f32_to_bf16(hi.y);
    w[6] = (short)f32_to_bf16(hi.z); w[7] = (short)f32_to_bf16(hi.w);
    return w;
}

// WtB[g][ks][n][c'][j]: granule c' of row n holds logical granule c'^((n>>1)&3)
// of Wt[n][ks*32..+32), so a LINEAR global_load_lds write produces the LDS
// slab read with granule ^= ((n>>1)&3).
__global__ __launch_bounds__(256) void convert_w1(const float* __restrict__ W1,
                                                  unsigned short* __restrict__ WtB) {
    int t = blockIdx.x * blockDim.x + threadIdx.x;
    if (t >= 2 * NK * 8192) return;
    int g  = t / (NK * 8192);
    int r  = t - g * (NK * 8192);
    int ks = r >> 13;
    int r2 = r & 8191;
    int n  = r2 >> 5;
    int w  = r2 & 31;
    int c  = (w >> 3) ^ ((n >> 1) & 3);
    int j  = w & 7;
    int k  = ks * BK + c * 8 + j;
    WtB[t] = f32_to_bf16(W1[(size_t)(g * IN_DIM + k) * HIDDEN + n]);
}

// P = bf16(X) @ bf16(W1half). Barrier-light streaming GEMM:
//  - wave = 32 m-rows x 256 n (acc[2][16]); A streamed global->reg->cvt->MFMA
//    (never LDS, never gates a barrier), 2-step reg prefetch.
//  - B: 16KB k-slab per step via pre-swizzled global_load_lds into a 4-slot
//    LDS ring; ONE bare s_barrier per step; counted vmcnt only.
__global__ __launch_bounds__(256, 2) void node_gemm(const float* __restrict__ X0,
                                                    const float* __restrict__ X1,
                                                    const unsigned short* __restrict__ WtB,
                                                    unsigned short* __restrict__ Pout,
                                                    unsigned short* __restrict__ Qout) {
    const int g = blockIdx.y;
    const float* __restrict__ X = g ? X1 : X0;
    unsigned short* __restrict__ Out = g ? Qout : Pout;
    const char* wtb = (const char*)WtB + (size_t)g * NK * WTB_TILE;

    __shared__ __attribute__((aligned(16))) char Bs[4 * WTB_TILE]; // 64 KB ring

    const int tid  = threadIdx.x;
    const int lane = tid & 63;
    const int wid  = tid >> 6;       // 0..3
    const int lr   = lane & 15;
    const int c    = lane >> 4;      // 0..3 (k-chunk)

    const int wbase = blockIdx.x * BM + wid * 32;
    int row0 = wbase + lr;       if (row0 >= N_NODES) row0 = N_NODES - 1;
    int row1 = wbase + 16 + lr;  if (row1 >= N_NODES) row1 = N_NODES - 1;
    const float* a0 = X + (size_t)row0 * IN_DIM + c * 8;
    const float* a1 = X + (size_t)row1 * IN_DIM + c * 8;

    // B staging source (linear, pre-swizzled) and LDS read base
    const char* bsrc = wtb + wid * 4096 + lane * 16;
    const int   bread = lr * 64 + ((c ^ ((lr >> 1) & 3)) << 4);
    char* const bdst  = Bs + wid * 4096;

    f32x4 acc[2][16] = {};
    float4 bankE[4], bankO[4];

#define ISSUE_A(KT, BANK) do {                                   \
        const float* _p0 = a0 + (KT) * BK;                       \
        const float* _p1 = a1 + (KT) * BK;                       \
        BANK[0] = *(const float4*)(_p0);                         \
        BANK[1] = *(const float4*)(_p0 + 4);                     \
        BANK[2] = *(const float4*)(_p1);                         \
        BANK[3] = *(const float4*)(_p1 + 4);                     \
    } while (0)

#define ISSUE_B(KT, SLOT) do {                                   \
        const char* _s = bsrc + (size_t)(KT) * WTB_TILE;         \
        char* _d = bdst + (SLOT) * WTB_TILE;                     \
        gload_lds16(_s,        _d);                              \
        gload_lds16(_s + 1024, _d + 1024);                       \
        gload_lds16(_s + 2048, _d + 2048);                       \
        gload_lds16(_s + 3072, _d + 3072);                       \
    } while (0)

    // KSTEP(s): cvt A(s) [compiler vmcnt-wait drains B(s) too: B(s) is older],
    // issue B(s+2)/A(s+2), WAITV(16) keeps exactly {B,A}(s+1),(s+2) in flight,
    // bare barrier, then 16 ds_read_b128 + 32 MFMA off ring slot s&3.
#define KSTEP(S, SLOTR, SLOTW, BANK) do {                        \
        short8 af0 = cvt8(BANK[0], BANK[1]);                     \
        short8 af1 = cvt8(BANK[2], BANK[3]);                     \
        int _kn = (S) + 2; if (_kn > NK - 1) _kn = NK - 1;       \
        ISSUE_B(_kn, SLOTW);                                     \
        ISSUE_A(_kn, BANK);                                      \
        WAITV(16);                                               \
        BAR();                                                   \
        const char* _bb = Bs + (SLOTR) * WTB_TILE + bread;       \
        __builtin_amdgcn_s_setprio(1);                           \
        _Pragma("unroll")                                        \
        for (int ni = 0; ni < 16; ++ni) {                        \
            short8 bf = *(const short8*)(_bb + ni * 1024);       \
            acc[0][ni] = __builtin_amdgcn_mfma_f32_16x16x32_bf16(bf, af0, acc[0][ni], 0, 0, 0); \
            acc[1][ni] = __builtin_amdgcn_mfma_f32_16x16x32_bf16(bf, af1, acc[1][ni], 0, 0, 0); \
        }                                                        \
        __builtin_amdgcn_s_setprio(0);                           \
    } while (0)

    // prologue: queue order per step is [B, A] — matches ledger
    ISSUE_B(0, 0); ISSUE_A(0, bankE);
    ISSUE_B(1, 1); ISSUE_A(1, bankO);

    for (int s = 0; s < NK; s += 4) {
        KSTEP(s + 0, 0, 2, bankE);
        KSTEP(s + 1, 1, 3, bankO);
        KSTEP(s + 2, 2, 0, bankE);
        KSTEP(s + 3, 3, 1, bankO);
    }

    // store: row = row0/row1 (clamped rows write duplicate values, benign),
    // n = ni*16 + c*4 + reg
#pragma unroll
    for (int ni = 0; ni < 16; ++ni) {
        f32x4 v0 = acc[0][ni], v1 = acc[1][ni];
        ushort4 w0, w1;
        w0.x = f32_to_bf16(v0[0]); w0.y = f32_to_bf16(v0[1]);
        w0.z = f32_to_bf16(v0[2]); w0.w = f32_to_bf16(v0[3]);
        w1.x = f32_to_bf16(v1[0]); w1.y = f32_to_bf16(v1[1]);
        w1.z = f32_to_bf16(v1[2]); w1.w = f32_to_bf16(v1[3]);
        *(ushort4*)(Out + (size_t)row0 * HIDDEN + ni * 16 + c * 4) = w0;
        *(ushort4*)(Out + (size_t)row1 * HIDDEN + ni * 16 + c * 4) = w1;
    }
    WAITV(0);   // drain tail gload_lds before LDS is reallocated
#undef KSTEP
#undef ISSUE_A
#undef ISSUE_B
}

// out[e] = relu(P[s]+Q[d]+b1) . W2 + b2 ; one wave per edge, lane j owns dims 4j..4j+3
__global__ __launch_bounds__(256) void edge_mlp(const unsigned short* __restrict__ P,
                                                const unsigned short* __restrict__ Q,
                                                const int* __restrict__ s_idx,
                                                const int* __restrict__ d_idx,
                                                const float* __restrict__ b1,
                                                const float* __restrict__ W2,
                                                const float* __restrict__ b2,
                                                float* __restrict__ out) {
    const int lane = threadIdx.x & 63;
    const int gw = (blockIdx.x * blockDim.x + threadIdx.x) >> 6;
    const int nw = (gridDim.x * blockDim.x) >> 6;
    const float4 b1v = *(const float4*)(b1 + lane * 4);
    const float4 w2v = *(const float4*)(W2 + lane * 4);
    const float b2s = *b2;
    for (int e = gw; e < N_EDGES; e += nw) {
        int s = s_idx[e];
        int d = d_idx[e];
        ushort4 pv = *(const ushort4*)(P + (size_t)s * HIDDEN + lane * 4);
        ushort4 qv = *(const ushort4*)(Q + (size_t)d * HIDDEN + lane * 4);
        float h, sum;
        h = bf16_to_f32(pv.x) + bf16_to_f32(qv.x) + b1v.x; h = fmaxf(h, 0.f); sum  = h * w2v.x;
        h = bf16_to_f32(pv.y) + bf16_to_f32(qv.y) + b1v.y; h = fmaxf(h, 0.f); sum += h * w2v.y;
        h = bf16_to_f32(pv.z) + bf16_to_f32(qv.z) + b1v.z; h = fmaxf(h, 0.f); sum += h * w2v.z;
        h = bf16_to_f32(pv.w) + bf16_to_f32(qv.w) + b1v.w; h = fmaxf(h, 0.f); sum += h * w2v.w;
#pragma unroll
        for (int off = 32; off; off >>= 1) sum += __shfl_xor(sum, off, 64);
        if (lane == 0) out[e] = sum + b2s;
    }
}

extern "C" void kernel_launch(void* const* d_in, const int* in_sizes, int n_in,
                              void* d_out, int out_size, void* d_ws, size_t ws_size,
                              hipStream_t stream) {
    const float* x_src = (const float*)d_in[0];
    const float* x_dst = (const float*)d_in[1];
    const int*   s_idx = (const int*)d_in[2];
    const int*   d_idx = (const int*)d_in[3];
    const float* W1    = (const float*)d_in[4];
    const float* b1    = (const float*)d_in[5];
    const float* W2    = (const float*)d_in[6];
    const float* b2    = (const float*)d_in[7];
    float* out = (float*)d_out;

    char* ws = (char*)d_ws;
    // layout: WtB (786432 B) | P (M_PAD*256*2 B) | Q (M_PAD*256*2 B) => ~103.3 MB
    unsigned short* WtB = (unsigned short*)ws;
    unsigned short* P   = (unsigned short*)(ws + 786432);
    unsigned short* Q   = (unsigned short*)(ws + 786432 + (size_t)M_PAD * HIDDEN * 2);

    convert_w1<<<(2 * NK * 8192 + 255) / 256, 256, 0, stream>>>(W1, WtB);

    dim3 gg(M_BLOCKS, 2);
    node_gemm<<<gg, 256, 0, stream>>>(x_src, x_dst, WtB, P, Q);

    edge_mlp<<<2048, 256, 0, stream>>>(P, Q, s_idx, d_idx, b1, W2, b2, out);
}